// Round 1
// baseline (3386.598 us; speedup 1.0000x reference)
//
#include <hip/hip_runtime.h>

// Seq2SeqRNN: 96 encoder GRU steps + 95 autoregressive decoder steps.
// Batch rows are independent across the whole recurrence -> partition batch
// across blocks, loop time inside the kernel. h and decoder feedback live in LDS.
//
// v1 (baseline): fp32 vector-ALU GEMV per step, weights streamed from L2 in a
// transposed+interleaved layout (packed into d_ws by a prep kernel) so weight
// loads are coalesced dwordx4 across lanes. Predicted ~L2-read-bound, ~850us.

#define BATCH 512
#define LIN_  96
#define LOUT_ 96
#define TSEQ  192
#define NUM_  64
#define EMB_  32
#define HID_  256
#define INS_  96            // IN_SIZE = NUM + EMB
#define KTOT_ 352           // INS_ + HID_
#define G3_   768           // 3*HID

#define BBLK    4           // batch rows per block
#define NBLOCKS (BATCH / BBLK)   // 128
#define NTHR    512         // 8 waves; waves 0-3 -> rows 0,1; waves 4-7 -> rows 2,3

#define WDEC_LD 257         // +1 pad: (m*257+k)%32 = (m+k)%32 -> 2-way (free)

__device__ __forceinline__ float fast_sigmoid(float x) {
    return 1.0f / (1.0f + __expf(-x));
}
__device__ __forceinline__ float fast_tanh(float x) {
    return 2.0f / (1.0f + __expf(-2.0f * x)) - 1.0f;
}

// Pack [W_ih | W_hh] (row-major [768,k]) into WT4[kb][j][kk]:
// WT4[kb*3072 + j*4 + kk] = W[j][kb*4+kk]  (k<96 -> W_ih, else W_hh).
// Lane j reads its 4-k chunk as one coalesced dwordx4.
__global__ void pack_weights(const float* __restrict__ W_ih,
                             const float* __restrict__ W_hh,
                             float* __restrict__ WT4) {
    int idx = blockIdx.x * blockDim.x + threadIdx.x;
    if (idx >= KTOT_ * G3_) return;
    int kb  = idx / (G3_ * 4);
    int rem = idx - kb * (G3_ * 4);
    int j   = rem >> 2;
    int kk  = rem & 3;
    int k   = kb * 4 + kk;
    WT4[idx] = (k < INS_) ? W_ih[j * INS_ + k] : W_hh[j * HID_ + (k - INS_)];
}

__device__ __forceinline__ float dot4(float acc, float4 w, float4 x) {
    acc = fmaf(w.x, x.x, acc);
    acc = fmaf(w.y, x.y, acc);
    acc = fmaf(w.z, x.z, acc);
    acc = fmaf(w.w, x.w, acc);
    return acc;
}

template <bool PACKED>
__global__ __launch_bounds__(NTHR) void gru_seq2seq(
    const float* __restrict__ input_num,   // [512,192,64]
    const int*   __restrict__ input_cat,   // [512,192]
    const float* __restrict__ emb_table,   // [512,32]
    const float* __restrict__ WT4,         // packed weights (if PACKED)
    const float* __restrict__ W_ih,        // [768,96]  (fallback)
    const float* __restrict__ W_hh,        // [768,256] (fallback)
    const float* __restrict__ b_ih,        // [768]
    const float* __restrict__ b_hh,        // [768]
    const float* __restrict__ W_dec,       // [64,256]
    const float* __restrict__ b_dec,       // [64]
    float*       __restrict__ out)         // [512,96,64]
{
    // xh row layout per batch row: [0:64) num/out_prev | [64:96) emb | [96:352) h
    __shared__ __align__(16) float xh[BBLK][KTOT_];
    __shared__ float wdec[NUM_ * WDEC_LD];

    const int t     = threadIdx.x;
    const int bbase = blockIdx.x * BBLK;
    const int u     = t & (HID_ - 1);      // hidden unit owned by this thread
    const int rb    = (t >> 8) * 2;        // first of the 2 rows this thread handles

    // Stage W_dec into LDS (64KB, lives for the whole kernel).
    for (int i = t; i < NUM_ * HID_; i += NTHR) {
        int m = i >> 8, k = i & (HID_ - 1);
        wdec[m * WDEC_LD + k] = W_dec[i];
    }
    // h0 = 0
    for (int i = t; i < BBLK * HID_; i += NTHR) {
        int r = i >> 8, k = i & (HID_ - 1);
        xh[r][INS_ + k] = 0.0f;
    }

    // Per-thread biases. PyTorch GRU: r gate rows [0,256), z [256,512), n [512,768).
    const float bR  = b_ih[u] + b_hh[u];
    const float bZ  = b_ih[HID_ + u] + b_hh[HID_ + u];
    const float bNX = b_ih[2 * HID_ + u];      // gx_n bias
    const float bNH = b_hh[2 * HID_ + u];      // gh_n bias (gets scaled by r)
    const float bD  = b_dec[t & (NUM_ - 1)];

    __syncthreads();

    // ---- one GRU step over this block's 4 rows (x already staged in xh) ----
    auto gru_step = [&]() {
        float aR0 = bR,  aR1 = bR;
        float aZ0 = bZ,  aZ1 = bZ;
        float aNX0 = bNX, aNX1 = bNX;
        float aNH0 = bNH, aNH1 = bNH;

        const float* xrow0 = xh[rb];
        const float* xrow1 = xh[rb + 1];

        // k in [0,96): input part (accumulates gx_n into aNX)
        #pragma unroll 4
        for (int kb = 0; kb < INS_ / 4; kb++) {
            float4 w0, w1, w2;
            if (PACKED) {
                const float* p = WT4 + (size_t)kb * (G3_ * 4) + u * 4;
                w0 = *(const float4*)(p);
                w1 = *(const float4*)(p + HID_ * 4);        // j = 256+u
                w2 = *(const float4*)(p + 2 * HID_ * 4);    // j = 512+u
            } else {
                int k4 = kb * 4;
                w0 = *(const float4*)&W_ih[(size_t)u * INS_ + k4];
                w1 = *(const float4*)&W_ih[(size_t)(HID_ + u) * INS_ + k4];
                w2 = *(const float4*)&W_ih[(size_t)(2 * HID_ + u) * INS_ + k4];
            }
            float4 x0 = *(const float4*)&xrow0[kb * 4];   // broadcast LDS read
            float4 x1 = *(const float4*)&xrow1[kb * 4];
            aR0  = dot4(aR0,  w0, x0);  aR1  = dot4(aR1,  w0, x1);
            aZ0  = dot4(aZ0,  w1, x0);  aZ1  = dot4(aZ1,  w1, x1);
            aNX0 = dot4(aNX0, w2, x0);  aNX1 = dot4(aNX1, w2, x1);
        }
        // k in [96,352): hidden part (accumulates gh_n into aNH)
        #pragma unroll 4
        for (int kb = INS_ / 4; kb < KTOT_ / 4; kb++) {
            float4 w0, w1, w2;
            if (PACKED) {
                const float* p = WT4 + (size_t)kb * (G3_ * 4) + u * 4;
                w0 = *(const float4*)(p);
                w1 = *(const float4*)(p + HID_ * 4);
                w2 = *(const float4*)(p + 2 * HID_ * 4);
            } else {
                int kh = kb * 4 - INS_;
                w0 = *(const float4*)&W_hh[(size_t)u * HID_ + kh];
                w1 = *(const float4*)&W_hh[(size_t)(HID_ + u) * HID_ + kh];
                w2 = *(const float4*)&W_hh[(size_t)(2 * HID_ + u) * HID_ + kh];
            }
            float4 x0 = *(const float4*)&xrow0[kb * 4];
            float4 x1 = *(const float4*)&xrow1[kb * 4];
            aR0  = dot4(aR0,  w0, x0);  aR1  = dot4(aR1,  w0, x1);
            aZ0  = dot4(aZ0,  w1, x0);  aZ1  = dot4(aZ1,  w1, x1);
            aNH0 = dot4(aNH0, w2, x0);  aNH1 = dot4(aNH1, w2, x1);
        }

        float hold0 = xrow0[INS_ + u];
        float hold1 = xrow1[INS_ + u];
        __syncthreads();   // all reads of xh (x and h) complete before h is overwritten
        {
            float rg = fast_sigmoid(aR0);
            float zg = fast_sigmoid(aZ0);
            float ng = fast_tanh(aNX0 + rg * aNH0);
            xh[rb][INS_ + u] = (1.0f - zg) * ng + zg * hold0;
        }
        {
            float rg = fast_sigmoid(aR1);
            float zg = fast_sigmoid(aZ1);
            float ng = fast_tanh(aNX1 + rg * aNH1);
            xh[rb + 1][INS_ + u] = (1.0f - zg) * ng + zg * hold1;
        }
        __syncthreads();   // h_new visible to everyone
    };

    // ---- decoder projection: out = h @ W_dec^T + b_dec; also feed back into xh ----
    auto project = [&](int pos) {
        if (t < BBLK * NUM_) {            // 256 tasks: (row, m)
            int r = t >> 6, m = t & (NUM_ - 1);
            const float* wrow = &wdec[m * WDEC_LD];
            const float* hrow = &xh[r][INS_];
            float acc = bD;
            #pragma unroll 8
            for (int k = 0; k < HID_; k += 4) {
                float4 h4 = *(const float4*)&hrow[k];   // broadcast (same addr per wave)
                acc = fmaf(wrow[k],     h4.x, acc);
                acc = fmaf(wrow[k + 1], h4.y, acc);
                acc = fmaf(wrow[k + 2], h4.z, acc);
                acc = fmaf(wrow[k + 3], h4.w, acc);
            }
            out[((size_t)(bbase + r) * LOUT_ + pos) * NUM_ + m] = acc;
            xh[r][m] = acc;               // feedback: next decoder input [0:64)
        }
        // no sync needed: writes go to x-region; next load's sync orders them
    };

    auto load_enc_x = [&](int tstep) {
        if (t < BBLK * NUM_) {            // numeric features
            int r = t >> 6, k = t & (NUM_ - 1);
            xh[r][k] = input_num[((size_t)(bbase + r) * TSEQ + tstep) * NUM_ + k];
        }
        if (t < BBLK * EMB_) {            // embedding gather
            int r = t >> 5, e = t & (EMB_ - 1);
            int cat = input_cat[(bbase + r) * TSEQ + tstep];
            xh[r][NUM_ + e] = emb_table[cat * EMB_ + e];
        }
        __syncthreads();
    };

    auto load_dec_emb = [&](int tstep) {
        if (t < BBLK * EMB_) {
            int r = t >> 5, e = t & (EMB_ - 1);
            int cat = input_cat[(bbase + r) * TSEQ + tstep];
            xh[r][NUM_ + e] = emb_table[cat * EMB_ + e];
        }
        __syncthreads();
    };

    // ======== encoder ========
    for (int step = 0; step < LIN_; step++) {
        load_enc_x(step);
        gru_step();
    }
    project(0);                           // out0 from final encoder h

    // ======== autoregressive decoder ========
    for (int s = 0; s < LOUT_ - 1; s++) {
        load_dec_emb(LIN_ + s);
        gru_step();
        project(s + 1);
    }
}

extern "C" void kernel_launch(void* const* d_in, const int* in_sizes, int n_in,
                              void* d_out, int out_size, void* d_ws, size_t ws_size,
                              hipStream_t stream) {
    const float* input_num = (const float*)d_in[0];
    const int*   input_cat = (const int*)d_in[1];
    const float* emb_table = (const float*)d_in[2];
    const float* W_ih      = (const float*)d_in[3];
    const float* W_hh      = (const float*)d_in[4];
    const float* b_ih      = (const float*)d_in[5];
    const float* b_hh      = (const float*)d_in[6];
    const float* W_dec     = (const float*)d_in[7];
    const float* b_dec     = (const float*)d_in[8];
    float* out = (float*)d_out;

    const size_t wt_bytes = (size_t)KTOT_ * G3_ * sizeof(float);  // ~1.06 MB
    if (ws_size >= wt_bytes) {
        float* WT4 = (float*)d_ws;
        int n = KTOT_ * G3_;
        pack_weights<<<(n + 255) / 256, 256, 0, stream>>>(W_ih, W_hh, WT4);
        gru_seq2seq<true><<<NBLOCKS, NTHR, 0, stream>>>(
            input_num, input_cat, emb_table, WT4, W_ih, W_hh,
            b_ih, b_hh, W_dec, b_dec, out);
    } else {
        // fallback: same math, weights read in original row-major layout
        gru_seq2seq<false><<<NBLOCKS, NTHR, 0, stream>>>(
            input_num, input_cat, emb_table, nullptr, W_ih, W_hh,
            b_ih, b_hh, W_dec, b_dec, out);
    }
}

// Round 4
// 2509.334 us; speedup vs baseline: 1.3496x; 1.3496x over previous
//
#include <hip/hip_runtime.h>

// Seq2SeqRNN v4: hidden-split cooperative GRU, weights in VGPRs, MFMA.
// 32 groups x 4 member-blocks (128 blocks total -> co-residency guaranteed).
// Group = 16 batch rows; member = 64 hidden units (192 gate rows = 12 j-tiles).
// 6 waves/block; wave w owns j-tiles {2w,2w+1}; gate weights held in VGPRs
// (loaded once from fp32 W_ih/W_hh). Per-step h exchange via d_ws (bf16,
// parity double-buffered), flag release/acquire with bounded spin.
// d_ws sync region zeroed by hipMemsetAsync (no prep kernel).

#define BATCH 512
#define TSEQ  192
#define LIN_  96
#define LOUT_ 96
#define NUM_  64
#define EMB_  32
#define HID_  256
#define INS_  96
#define KT_   352

#define NBLK  128
#define NT    384          // 6 waves
#define XSTR  360          // bf16 row stride for [x(96)|h(256)] operand (720B, 16B-aligned)
#define GSTR  66           // fp32 gate-buffer row stride
#define SPIN_CAP 4194304u  // bounded spin: breaks (finite wrong output) instead of hanging

#define WS_NEED 528384u    // 4096 (flags) + 32*2*1024*8 (exchange)

typedef __attribute__((ext_vector_type(8))) short short8_t;
typedef __attribute__((ext_vector_type(4))) float float4_t;
typedef unsigned long long ull;
typedef unsigned short us;

__device__ __forceinline__ us f2bf(float x) {
    unsigned u = __builtin_bit_cast(unsigned, x);
    u = (u + 0x7FFFu + ((u >> 16) & 1u)) >> 16;
    return (us)u;
}
__device__ __forceinline__ float sigm(float x)  { return 1.0f / (1.0f + __expf(-x)); }
__device__ __forceinline__ float tanhx(float x) { return 2.0f / (1.0f + __expf(-2.0f * x)) - 1.0f; }

__device__ __forceinline__ short8_t pack8(const float* v) {
    short8_t s;
    #pragma unroll
    for (int j = 0; j < 8; ++j) s[j] = (short)f2bf(v[j]);
    return s;
}

__global__ __launch_bounds__(NT) void gru_v4(
    const float* __restrict__ input_num, const int* __restrict__ input_cat,
    const float* __restrict__ emb_table,
    const float* __restrict__ W_ih, const float* __restrict__ W_hh,
    const float* __restrict__ b_ih, const float* __restrict__ b_hh,
    const float* __restrict__ W_dec, const float* __restrict__ b_dec,
    unsigned* __restrict__ flags, ull* __restrict__ xb,
    float* __restrict__ out)
{
    __shared__ __align__(16) us XH[16 * XSTR];          // [x(0..95) | h(96..351)] bf16
    __shared__ float gR[16 * GSTR], gZ[16 * GSTR], gNX[16 * GSTR], gNH[16 * GSTR];
    __shared__ float hloc[1024];                        // own 64 units x 16 rows fp32
    __shared__ __align__(16) us hbf[1024];              // same, bf16
    __shared__ float bRs[64], bZs[64], bNXs[64], bNHs[64], bDs[64];

    const int b = blockIdx.x, g = b >> 2, memb = b & 3, bb = g * 16;
    const int t = threadIdx.x, wave = t >> 6, lane = t & 63;
    const int arow = lane & 15, quad = lane >> 4, kq = quad * 8, col = lane & 15;
    unsigned* fgrp = flags + g * 8;                     // [parity*4 + memb]
    ull* xg = xb + (size_t)g * 2048;                    // [parity*1024 + row*64 + memb*16 + q]

    // ---- one-time: gate weight fragments -> VGPRs (fp32 -> bf16 in-register) ----
    // j-tiles 0-3: r rows 64*memb+{0,16,32,48}; 4-7: z (+256); 8-11: n (+512).
    short8_t wfrag[2][11];
    #pragma unroll
    for (int ti = 0; ti < 2; ++ti) {
        const int tt = 2 * wave + ti;
        const int grow = (tt >> 2) * HID_ + 64 * memb + (tt & 3) * 16 + arow;
        #pragma unroll
        for (int kc = 0; kc < 11; ++kc) {
            float tmp[8];
            #pragma unroll
            for (int j2 = 0; j2 < 2; ++j2) {
                const int k = kc * 32 + kq + j2 * 4;    // chunk never straddles the 96 boundary
                float4 v = (k < INS_) ? *(const float4*)&W_ih[(size_t)grow * INS_ + k]
                                      : *(const float4*)&W_hh[(size_t)grow * HID_ + (k - INS_)];
                tmp[j2 * 4 + 0] = v.x; tmp[j2 * 4 + 1] = v.y;
                tmp[j2 * 4 + 2] = v.z; tmp[j2 * 4 + 3] = v.w;
            }
            wfrag[ti][kc] = pack8(tmp);
        }
    }
    // W_dec fragments (used by waves 0-3; waves 4/5 load duplicates to stay in-bounds)
    short8_t wd[8];
    {
        const int nrow = (wave & 3) * 16 + arow;
        #pragma unroll
        for (int kc = 0; kc < 8; ++kc) {
            float tmp[8];
            #pragma unroll
            for (int j2 = 0; j2 < 2; ++j2) {
                float4 v = *(const float4*)&W_dec[(size_t)nrow * HID_ + kc * 32 + kq + j2 * 4];
                tmp[j2 * 4 + 0] = v.x; tmp[j2 * 4 + 1] = v.y;
                tmp[j2 * 4 + 2] = v.z; tmp[j2 * 4 + 3] = v.w;
            }
            wd[kc] = pack8(tmp);
        }
    }

    // ---- one-time LDS init ----
    for (int c = t; c < 16 * XSTR; c += NT) XH[c] = 0;
    for (int c = t; c < 1024; c += NT) { hloc[c] = 0.0f; hbf[c] = 0; }
    if (t < 64) {
        const int u = t, gu = 64 * memb + u;
        bRs[u]  = b_ih[gu] + b_hh[gu];
        bZs[u]  = b_ih[HID_ + gu] + b_hh[HID_ + gu];
        bNXs[u] = b_ih[2 * HID_ + gu];
        bNHs[u] = b_hh[2 * HID_ + gu];
    } else if (t < 128) {
        bDs[t - 64] = b_dec[t - 64];
    }
    __syncthreads();

    // ======== 191 sequential GRU steps ========
    for (int sg = 1; sg <= 191; ++sg) {
        const int tstep = sg - 1;

        // (A) stage x columns. Layout is the NATURAL W_ih order for both phases:
        //     cols 0..63 = input_num (enc) / out_prev (dec, written in phase C);
        //     cols 64..95 = embedding.
        if (sg <= 96) {
            if (t < 256) {
                const int row = t >> 4, q = t & 15;
                float4 v = *(const float4*)&input_num[((size_t)(bb + row) * TSEQ + tstep) * NUM_ + q * 4];
                ushort4 s = { f2bf(v.x), f2bf(v.y), f2bf(v.z), f2bf(v.w) };
                *(ushort4*)&XH[row * XSTR + q * 4] = s;
            } else {
                const int e = t - 256, row = e >> 3, q = e & 7;
                const int cat = input_cat[(bb + row) * TSEQ + tstep];
                float4 v = *(const float4*)&emb_table[cat * EMB_ + q * 4];
                ushort4 s = { f2bf(v.x), f2bf(v.y), f2bf(v.z), f2bf(v.w) };
                *(ushort4*)&XH[row * XSTR + NUM_ + q * 4] = s;
            }
        } else if (t < 128) {
            const int row = t >> 3, q = t & 7;
            const int cat = input_cat[(bb + row) * TSEQ + tstep];
            float4 v = *(const float4*)&emb_table[cat * EMB_ + q * 4];
            ushort4 s = { f2bf(v.x), f2bf(v.y), f2bf(v.z), f2bf(v.w) };
            *(ushort4*)&XH[row * XSTR + NUM_ + q * 4] = s;
        }

        // (B) wait for peers' step sg-1 and pull full H_{sg-1}
        if (sg > 1) {
            const int par = (sg - 1) & 1;
            if (t < 4) {
                const unsigned tgt = (unsigned)(sg - 1);
                unsigned cnt = 0;
                while (__hip_atomic_load(&fgrp[par * 4 + t], __ATOMIC_ACQUIRE,
                                         __HIP_MEMORY_SCOPE_AGENT) < tgt) {
                    if (++cnt > SPIN_CAP) break;   // diagnostic bail-out, never a hang
                }
            }
            __syncthreads();
            const ull* src = xg + par * 1024;
            for (int c = t; c < 1024; c += NT) {
                ull v = __hip_atomic_load(&src[c], __ATOMIC_RELAXED, __HIP_MEMORY_SCOPE_AGENT);
                *(ull*)&XH[(c >> 6) * XSTR + INS_ + (c & 63) * 4] = v;
            }
        }
        __syncthreads();

        // (C) decoder: out_{sg-97} = H_{sg-1} @ W_dec^T + b_dec; feedback into cols 0..63
        if (sg > 96) {
            if (wave < 4) {
                float4_t acc = {0.f, 0.f, 0.f, 0.f};
                #pragma unroll
                for (int kc = 0; kc < 8; ++kc) {
                    short8_t a = *(const short8_t*)&XH[arow * XSTR + INS_ + kc * 32 + kq];
                    acc = __builtin_amdgcn_mfma_f32_16x16x32_bf16(a, wd[kc], acc, 0, 0, 0);
                }
                const int cg = wave * 16 + col, pos = sg - 97;
                const float bia = bDs[cg];
                #pragma unroll
                for (int i = 0; i < 4; ++i) {
                    const int row = quad * 4 + i;
                    const float val = acc[i] + bia;
                    XH[row * XSTR + cg] = f2bf(val);
                    if (memb == wave)
                        out[((size_t)(bb + row) * LOUT_ + pos) * NUM_ + cg] = val;
                }
            }
            __syncthreads();
        }

        // (D) gate MFMAs: wave w -> j-tiles {2w, 2w+1}; waves 0/1=r, 2/3=z, 4/5=n
        {
            short8_t a[11];
            #pragma unroll
            for (int kc = 0; kc < 11; ++kc)
                a[kc] = *(const short8_t*)&XH[arow * XSTR + kc * 32 + kq];
            const int u0 = ((2 * wave) & 3) * 16 + col;
            const int u1 = ((2 * wave + 1) & 3) * 16 + col;
            if (wave < 4) {                       // r and z: gx+gh combined
                float4_t a0 = {0.f,0.f,0.f,0.f}, a1 = {0.f,0.f,0.f,0.f};
                #pragma unroll
                for (int kc = 0; kc < 11; ++kc) {
                    a0 = __builtin_amdgcn_mfma_f32_16x16x32_bf16(a[kc], wfrag[0][kc], a0, 0, 0, 0);
                    a1 = __builtin_amdgcn_mfma_f32_16x16x32_bf16(a[kc], wfrag[1][kc], a1, 0, 0, 0);
                }
                float* dst = (wave < 2) ? gR : gZ;
                #pragma unroll
                for (int i = 0; i < 4; ++i) {
                    const int row = quad * 4 + i;
                    dst[row * GSTR + u0] = a0[i];
                    dst[row * GSTR + u1] = a1[i];
                }
            } else {                              // n: gx and gh kept separate
                float4_t x0 = {0.f,0.f,0.f,0.f}, h0 = {0.f,0.f,0.f,0.f};
                float4_t x1 = {0.f,0.f,0.f,0.f}, h1 = {0.f,0.f,0.f,0.f};
                #pragma unroll
                for (int kc = 0; kc < 3; ++kc) {
                    x0 = __builtin_amdgcn_mfma_f32_16x16x32_bf16(a[kc], wfrag[0][kc], x0, 0, 0, 0);
                    x1 = __builtin_amdgcn_mfma_f32_16x16x32_bf16(a[kc], wfrag[1][kc], x1, 0, 0, 0);
                }
                #pragma unroll
                for (int kc = 3; kc < 11; ++kc) {
                    h0 = __builtin_amdgcn_mfma_f32_16x16x32_bf16(a[kc], wfrag[0][kc], h0, 0, 0, 0);
                    h1 = __builtin_amdgcn_mfma_f32_16x16x32_bf16(a[kc], wfrag[1][kc], h1, 0, 0, 0);
                }
                #pragma unroll
                for (int i = 0; i < 4; ++i) {
                    const int row = quad * 4 + i;
                    gNX[row * GSTR + u0] = x0[i];  gNH[row * GSTR + u0] = h0[i];
                    gNX[row * GSTR + u1] = x1[i];  gNH[row * GSTR + u1] = h1[i];
                }
            }
        }
        __syncthreads();

        // (E) pointwise GRU cell: 1024 tasks = 16 rows x 64 own units
        for (int task = t; task < 1024; task += NT) {
            const int row = task >> 6, u = task & 63;
            const float r  = sigm(gR[row * GSTR + u] + bRs[u]);
            const float z  = sigm(gZ[row * GSTR + u] + bZs[u]);
            const float n  = tanhx(gNX[row * GSTR + u] + bNXs[u]
                                   + r * (gNH[row * GSTR + u] + bNHs[u]));
            const float hn = (1.0f - z) * n + z * hloc[task];
            hloc[task] = hn;
            hbf[task]  = f2bf(hn);
        }
        __syncthreads();

        // (F) publish own 64-unit slice, fence, release flag
        {
            ull* dst = xg + (sg & 1) * 1024;
            if (t < 256) {
                const int row = t >> 4, q = t & 15;
                ull v = *(const ull*)&hbf[row * 64 + q * 4];
                __hip_atomic_store(&dst[row * 64 + memb * 16 + q], v,
                                   __ATOMIC_RELAXED, __HIP_MEMORY_SCOPE_AGENT);
                __threadfence();
            }
            __syncthreads();
            if (t == 0)
                __hip_atomic_store(&fgrp[(sg & 1) * 4 + memb], (unsigned)sg,
                                   __ATOMIC_RELEASE, __HIP_MEMORY_SCOPE_AGENT);
        }
    }

    // ======== epilogue: out position 95 from H_191 ========
    if (t < 4) {
        unsigned cnt = 0;
        while (__hip_atomic_load(&fgrp[4 + t], __ATOMIC_ACQUIRE,
                                 __HIP_MEMORY_SCOPE_AGENT) < 191u) {
            if (++cnt > SPIN_CAP) break;
        }
    }
    __syncthreads();
    {
        const ull* src = xg + 1024;   // parity of step 191 is 1
        for (int c = t; c < 1024; c += NT) {
            ull v = __hip_atomic_load(&src[c], __ATOMIC_RELAXED, __HIP_MEMORY_SCOPE_AGENT);
            *(ull*)&XH[(c >> 6) * XSTR + INS_ + (c & 63) * 4] = v;
        }
    }
    __syncthreads();
    if (wave < 4 && memb == wave) {
        float4_t acc = {0.f, 0.f, 0.f, 0.f};
        #pragma unroll
        for (int kc = 0; kc < 8; ++kc) {
            short8_t a = *(const short8_t*)&XH[arow * XSTR + INS_ + kc * 32 + kq];
            acc = __builtin_amdgcn_mfma_f32_16x16x32_bf16(a, wd[kc], acc, 0, 0, 0);
        }
        const int cg = wave * 16 + col;
        const float bia = bDs[cg];
        #pragma unroll
        for (int i = 0; i < 4; ++i) {
            const int row = quad * 4 + i;
            out[((size_t)(bb + row) * LOUT_ + 95) * NUM_ + cg] = acc[i] + bia;
        }
    }
}

// ============ fallback (v1 logic, known-passing fp32) if ws too small ============
__global__ __launch_bounds__(512) void gru_fallback(
    const float* __restrict__ input_num, const int* __restrict__ input_cat,
    const float* __restrict__ emb_table,
    const float* __restrict__ W_ih, const float* __restrict__ W_hh,
    const float* __restrict__ b_ih, const float* __restrict__ b_hh,
    const float* __restrict__ W_dec, const float* __restrict__ b_dec,
    float* __restrict__ out)
{
    __shared__ __align__(16) float xh[4][352];
    __shared__ float wdec[NUM_ * 257];
    const int t = threadIdx.x, bbase = blockIdx.x * 4;
    const int u = t & 255, rb = (t >> 8) * 2;
    for (int i = t; i < NUM_ * HID_; i += 512) wdec[(i >> 8) * 257 + (i & 255)] = W_dec[i];
    for (int i = t; i < 4 * HID_; i += 512) xh[i >> 8][INS_ + (i & 255)] = 0.0f;
    const float bR = b_ih[u] + b_hh[u], bZ = b_ih[256 + u] + b_hh[256 + u];
    const float bNX = b_ih[512 + u], bNH = b_hh[512 + u], bD = b_dec[t & 63];
    __syncthreads();
    auto step = [&]() {
        float aR0 = bR, aR1 = bR, aZ0 = bZ, aZ1 = bZ, aNX0 = bNX, aNX1 = bNX, aNH0 = bNH, aNH1 = bNH;
        const float* x0 = xh[rb]; const float* x1 = xh[rb + 1];
        for (int kb = 0; kb < 88; ++kb) {
            float4 w0, w1, w2; int k4 = kb * 4;
            if (k4 < INS_) {
                w0 = *(const float4*)&W_ih[(size_t)u * INS_ + k4];
                w1 = *(const float4*)&W_ih[(size_t)(256 + u) * INS_ + k4];
                w2 = *(const float4*)&W_ih[(size_t)(512 + u) * INS_ + k4];
            } else {
                int kh = k4 - INS_;
                w0 = *(const float4*)&W_hh[(size_t)u * HID_ + kh];
                w1 = *(const float4*)&W_hh[(size_t)(256 + u) * HID_ + kh];
                w2 = *(const float4*)&W_hh[(size_t)(512 + u) * HID_ + kh];
            }
            float4 a = *(const float4*)&x0[k4], c = *(const float4*)&x1[k4];
            aR0 += w0.x*a.x+w0.y*a.y+w0.z*a.z+w0.w*a.w; aR1 += w0.x*c.x+w0.y*c.y+w0.z*c.z+w0.w*c.w;
            aZ0 += w1.x*a.x+w1.y*a.y+w1.z*a.z+w1.w*a.w; aZ1 += w1.x*c.x+w1.y*c.y+w1.z*c.z+w1.w*c.w;
            if (k4 < INS_) { aNX0 += w2.x*a.x+w2.y*a.y+w2.z*a.z+w2.w*a.w; aNX1 += w2.x*c.x+w2.y*c.y+w2.z*c.z+w2.w*c.w; }
            else           { aNH0 += w2.x*a.x+w2.y*a.y+w2.z*a.z+w2.w*a.w; aNH1 += w2.x*c.x+w2.y*c.y+w2.z*c.z+w2.w*c.w; }
        }
        float h0 = x0[INS_ + u], h1 = x1[INS_ + u];
        __syncthreads();
        { float r = sigm(aR0), z = sigm(aZ0), n = tanhx(aNX0 + r * aNH0);
          xh[rb][INS_ + u] = (1 - z) * n + z * h0; }
        { float r = sigm(aR1), z = sigm(aZ1), n = tanhx(aNX1 + r * aNH1);
          xh[rb + 1][INS_ + u] = (1 - z) * n + z * h1; }
        __syncthreads();
    };
    auto project = [&](int pos) {
        if (t < 256) {
            int r = t >> 6, m = t & 63;
            const float* wr = &wdec[m * 257]; const float* hr = &xh[r][INS_];
            float acc = bD;
            for (int k = 0; k < HID_; ++k) acc = fmaf(wr[k], hr[k], acc);
            out[((size_t)(bbase + r) * LOUT_ + pos) * NUM_ + m] = acc;
            xh[r][m] = acc;
        }
    };
    for (int s = 0; s < LIN_; ++s) {
        if (t < 256) { int r = t >> 6, k = t & 63;
            xh[r][k] = input_num[((size_t)(bbase + r) * TSEQ + s) * NUM_ + k]; }
        if (t < 128) { int r = t >> 5, e = t & 31;
            xh[r][NUM_ + e] = emb_table[input_cat[(bbase + r) * TSEQ + s] * EMB_ + e]; }
        __syncthreads();
        step();
    }
    project(0);
    for (int s = 0; s < LOUT_ - 1; ++s) {
        if (t < 128) { int r = t >> 5, e = t & 31;
            xh[r][NUM_ + e] = emb_table[input_cat[(bbase + r) * TSEQ + LIN_ + s] * EMB_ + e]; }
        __syncthreads();
        step();
        project(s + 1);
    }
}

extern "C" void kernel_launch(void* const* d_in, const int* in_sizes, int n_in,
                              void* d_out, int out_size, void* d_ws, size_t ws_size,
                              hipStream_t stream) {
    const float* input_num = (const float*)d_in[0];
    const int*   input_cat = (const int*)d_in[1];
    const float* emb_table = (const float*)d_in[2];
    const float* W_ih      = (const float*)d_in[3];
    const float* W_hh      = (const float*)d_in[4];
    const float* b_ih      = (const float*)d_in[5];
    const float* b_hh      = (const float*)d_in[6];
    const float* W_dec     = (const float*)d_in[7];
    const float* b_dec     = (const float*)d_in[8];
    float* out = (float*)d_out;

    if (ws_size >= WS_NEED) {
        // zero flags + exchange region (graph-capturable async memset)
        hipMemsetAsync(d_ws, 0, WS_NEED, stream);
        unsigned* flags = (unsigned*)d_ws;
        ull* xb = (ull*)((char*)d_ws + 4096);
        gru_v4<<<NBLK, NT, 0, stream>>>(input_num, input_cat, emb_table,
                                        W_ih, W_hh, b_ih, b_hh, W_dec, b_dec,
                                        flags, xb, out);
    } else {
        gru_fallback<<<BATCH / 4, 512, 0, stream>>>(input_num, input_cat, emb_table,
                                                    W_ih, W_hh, b_ih, b_hh, W_dec, b_dec, out);
    }
}

// Round 5
// 1099.428 us; speedup vs baseline: 3.0803x; 2.2824x over previous
//
#include <hip/hip_runtime.h>

// Seq2SeqRNN v5: fully block-local GRU. 32 blocks x 512 threads; each block owns
// 16 batch rows and the FULL weight set (VGPR frags + LDS + small L2 stream).
// ZERO cross-block communication (v4's 13us/step sync latency eliminated).
// Per wave: 2 unit-tiles (32 hidden units); r/z/nx/nh C-frags for the same unit
// slice live in the same wave -> pointwise GRU cell is pure-register.

#define BATCH 512
#define TSEQ  192
#define LIN_  96
#define LOUT_ 96
#define NUM_  64
#define EMB_  32
#define HID_  256
#define INS_  96

#define NBLK  32
#define NT    512          // 8 waves, 2/SIMD -> 256 VGPR budget
#define XSTR  360          // bf16 stride, XH[16][x(96)|h(256)] rows (720 B, 16B-aligned)
#define WLSTR 72           // bf16 stride, WL rows (144 B, 16B-aligned)
#define WDSTR 264          // bf16 stride, WD rows (528 B, 16B-aligned)

// ws layout: bf16 image of W cols k=192..351 (chunks 6-10) + W_dec image.
#define WS_W2   0u         // [768][160] bf16 = 245760 B
#define WS_WDEC 245760u    // [64][256]  bf16 = 32768 B
#define WS_NEED 278528u    // <= 516KB proven available in R4

typedef __attribute__((ext_vector_type(8))) short short8_t;
typedef __attribute__((ext_vector_type(4))) float float4_t;
typedef unsigned short us;

__device__ __forceinline__ us f2bf(float x) {
    unsigned u = __builtin_bit_cast(unsigned, x);
    u = (u + 0x7FFFu + ((u >> 16) & 1u)) >> 16;
    return (us)u;
}
__device__ __forceinline__ float sigm(float x)  { return 1.0f / (1.0f + __expf(-x)); }
__device__ __forceinline__ float tanhx(float x) { return 2.0f / (1.0f + __expf(-2.0f * x)) - 1.0f; }

__device__ __forceinline__ short8_t pack8(const float* v) {
    short8_t s;
    #pragma unroll
    for (int j = 0; j < 8; ++j) s[j] = (short)f2bf(v[j]);
    return s;
}

#define MFMA16(a, b, c) __builtin_amdgcn_mfma_f32_16x16x32_bf16((a), (b), (c), 0, 0, 0)

// ============ prep: bf16 images of streamed/LDS weight slice + W_dec ============
__global__ void prep_v5(const float* __restrict__ W_hh, const float* __restrict__ W_dec,
                        unsigned char* __restrict__ ws) {
    us* W2    = (us*)(ws + WS_W2);      // [768][160]: col c <-> k=192+c <-> W_hh col 96+c
    us* WdecB = (us*)(ws + WS_WDEC);    // [64][256]
    const int i = blockIdx.x * 256 + threadIdx.x;
    if (i < 768 * 160) {
        const int row = i / 160, c = i - row * 160;
        W2[i] = f2bf(W_hh[row * HID_ + INS_ + c]);
    } else if (i < 768 * 160 + 64 * 256) {
        const int x = i - 768 * 160;
        WdecB[x] = f2bf(W_dec[x]);
    }
}

// ============ main: one self-sufficient block per 16 batch rows ============
__global__ __launch_bounds__(NT, 2) void gru_v5(
    const float* __restrict__ input_num, const int* __restrict__ input_cat,
    const float* __restrict__ emb_table,
    const float* __restrict__ W_ih, const float* __restrict__ W_hh,
    const float* __restrict__ b_ih, const float* __restrict__ b_hh,
    const float* __restrict__ b_dec,
    const unsigned char* __restrict__ ws, float* __restrict__ out)
{
    __shared__ __align__(16) us XH[16 * XSTR];       // operand: [x 0..95 | h 96..351]
    __shared__ __align__(16) us WL[768 * WLSTR];     // gate-W k-chunks 6,7 (k=192..255)
    __shared__ __align__(16) us WD[64 * WDSTR];      // W_dec bf16

    const us* W2    = (const us*)(ws + WS_W2);
    const us* WdecB = (const us*)(ws + WS_WDEC);

    const int t = threadIdx.x, wave = t >> 6, lane = t & 63;
    const int arow = lane & 15, quad = lane >> 4, kq = quad * 8;
    const int bb = blockIdx.x * 16;

    // ---- one-time: VGPR gate-weight frags, k-chunks 0..5 (fp32 -> bf16 in-reg) ----
    // wave owns unit-tiles {2w, 2w+1}; gate g3 row-tile base = g3*256 + 32w + 16ti.
    short8_t wfr[2][3][6];
    #pragma unroll
    for (int ti = 0; ti < 2; ++ti) {
        #pragma unroll
        for (int g3 = 0; g3 < 3; ++g3) {
            const int grow = g3 * HID_ + 32 * wave + 16 * ti + arow;
            #pragma unroll
            for (int kc = 0; kc < 6; ++kc) {
                float tmp[8];
                #pragma unroll
                for (int j2 = 0; j2 < 2; ++j2) {
                    const int k = kc * 32 + kq + j2 * 4;   // < 192; never straddles 96
                    float4 v = (k < INS_)
                        ? *(const float4*)&W_ih[(size_t)grow * INS_ + k]
                        : *(const float4*)&W_hh[(size_t)grow * HID_ + (k - INS_)];
                    tmp[j2 * 4 + 0] = v.x; tmp[j2 * 4 + 1] = v.y;
                    tmp[j2 * 4 + 2] = v.z; tmp[j2 * 4 + 3] = v.w;
                }
                wfr[ti][g3][kc] = pack8(tmp);
            }
        }
    }

    // ---- one-time: LDS staging ----
    for (int c = t; c < 768 * 8; c += NT) {          // WL <- W2 cols 0..63 (k 192..255)
        const int row = c >> 3, q = c & 7;
        *(ulonglong2*)&WL[row * WLSTR + q * 8] = *(const ulonglong2*)&W2[row * 160 + q * 8];
    }
    for (int c = t; c < 64 * 32; c += NT) {          // WD <- WdecB
        const int row = c >> 5, q = c & 31;
        *(ulonglong2*)&WD[row * WDSTR + q * 8] = *(const ulonglong2*)&WdecB[row * 256 + q * 8];
    }
    for (int c = t; c < 16 * XSTR; c += NT) XH[c] = 0;

    // ---- one-time: per-lane biases (unit u = 32w + 16ti + (lane&15)) ----
    float bRr[2], bZr[2], bNXr[2], bNHr[2];
    #pragma unroll
    for (int ti = 0; ti < 2; ++ti) {
        const int u = 32 * wave + 16 * ti + arow;
        bRr[ti]  = b_ih[u] + b_hh[u];
        bZr[ti]  = b_ih[HID_ + u] + b_hh[HID_ + u];
        bNXr[ti] = b_ih[2 * HID_ + u];
        bNHr[ti] = b_hh[2 * HID_ + u];
    }
    const float bdr = (wave < 4) ? b_dec[wave * 16 + arow] : 0.0f;
    float hr[2][4] = {{0.f,0.f,0.f,0.f},{0.f,0.f,0.f,0.f}};
    __syncthreads();

    // ======== 191 sequential GRU steps, all block-local ========
    for (int sg = 1; sg <= 191; ++sg) {
        const int tstep = sg - 1;

        // (A) stage x: enc = num(0..63)+emb(64..95); dec = emb only (feedback fills 0..63)
        if (sg <= 96) {
            if (t < 256) {
                const int row = t >> 4, q = t & 15;
                float4 v = *(const float4*)&input_num[((size_t)(bb + row) * TSEQ + tstep) * NUM_ + q * 4];
                ushort4 s = { f2bf(v.x), f2bf(v.y), f2bf(v.z), f2bf(v.w) };
                *(ushort4*)&XH[row * XSTR + q * 4] = s;
            } else if (t < 384) {
                const int e = t - 256, row = e >> 3, q = e & 7;
                const int cat = input_cat[(bb + row) * TSEQ + tstep];
                float4 v = *(const float4*)&emb_table[cat * EMB_ + q * 4];
                ushort4 s = { f2bf(v.x), f2bf(v.y), f2bf(v.z), f2bf(v.w) };
                *(ushort4*)&XH[row * XSTR + NUM_ + q * 4] = s;
            }
        } else if (t < 128) {
            const int row = t >> 3, q = t & 7;
            const int cat = input_cat[(bb + row) * TSEQ + tstep];
            float4 v = *(const float4*)&emb_table[cat * EMB_ + q * 4];
            ushort4 s = { f2bf(v.x), f2bf(v.y), f2bf(v.z), f2bf(v.w) };
            *(ushort4*)&XH[row * XSTR + NUM_ + q * 4] = s;
        }
        __syncthreads();   // B1: x + prev h visible

        // (C) decoder: out_{sg-97} = h_{sg-1} @ W_dec^T + b_dec; feedback -> XH[0..63]
        if (sg > 96) {
            if (wave < 4) {
                float4_t acc = {0.f, 0.f, 0.f, 0.f};
                #pragma unroll
                for (int kc = 0; kc < 8; ++kc) {
                    short8_t a = *(const short8_t*)&XH[arow * XSTR + INS_ + kc * 32 + kq];
                    short8_t b = *(const short8_t*)&WD[(wave * 16 + arow) * WDSTR + kc * 32 + kq];
                    acc = MFMA16(a, b, acc);
                }
                const int cg = wave * 16 + arow, pos = sg - 97;
                #pragma unroll
                for (int i = 0; i < 4; ++i) {
                    const int row = quad * 4 + i;
                    const float val = acc[i] + bdr;
                    XH[row * XSTR + cg] = f2bf(val);
                    out[((size_t)(bb + row) * LOUT_ + pos) * NUM_ + cg] = val;
                }
            }
            __syncthreads();   // B2: feedback visible
        }

        // (D)+(E) gates + pure-register pointwise, per unit-tile
        #pragma unroll
        for (int ti = 0; ti < 2; ++ti) {
            // prefetch streamed B-frags (k-chunks 8..10 from W2 cols 64..159, L2-hot)
            short8_t sw[3][3];
            #pragma unroll
            for (int g3 = 0; g3 < 3; ++g3) {
                const int grow = g3 * HID_ + 32 * wave + 16 * ti + arow;
                #pragma unroll
                for (int sc = 0; sc < 3; ++sc)
                    sw[g3][sc] = *(const short8_t*)&W2[(size_t)grow * 160 + 64 + sc * 32 + kq];
            }
            float4_t aR = {0.f,0.f,0.f,0.f}, aZ = {0.f,0.f,0.f,0.f};
            float4_t aNX = {0.f,0.f,0.f,0.f}, aNH = {0.f,0.f,0.f,0.f};
            #pragma unroll
            for (int kc = 0; kc < 6; ++kc) {          // VGPR-resident chunks
                short8_t a = *(const short8_t*)&XH[arow * XSTR + kc * 32 + kq];
                aR = MFMA16(a, wfr[ti][0][kc], aR);
                aZ = MFMA16(a, wfr[ti][1][kc], aZ);
                if (kc < 3) aNX = MFMA16(a, wfr[ti][2][kc], aNX);   // x-part of n
                else        aNH = MFMA16(a, wfr[ti][2][kc], aNH);   // h-part of n
            }
            #pragma unroll
            for (int kc = 6; kc < 8; ++kc) {          // LDS-resident chunks
                short8_t a = *(const short8_t*)&XH[arow * XSTR + kc * 32 + kq];
                const int wbase = 32 * wave + 16 * ti + arow;
                short8_t b0 = *(const short8_t*)&WL[(0 * HID_ + wbase) * WLSTR + (kc - 6) * 32 + kq];
                short8_t b1 = *(const short8_t*)&WL[(1 * HID_ + wbase) * WLSTR + (kc - 6) * 32 + kq];
                short8_t b2 = *(const short8_t*)&WL[(2 * HID_ + wbase) * WLSTR + (kc - 6) * 32 + kq];
                aR = MFMA16(a, b0, aR);
                aZ = MFMA16(a, b1, aZ);
                aNH = MFMA16(a, b2, aNH);
            }
            #pragma unroll
            for (int sc = 0; sc < 3; ++sc) {          // streamed chunks
                short8_t a = *(const short8_t*)&XH[arow * XSTR + (8 + sc) * 32 + kq];
                aR = MFMA16(a, sw[0][sc], aR);
                aZ = MFMA16(a, sw[1][sc], aZ);
                aNH = MFMA16(a, sw[2][sc], aNH);
            }
            // pointwise GRU cell (in-register; C-frag: unit=32w+16ti+arow, row=quad*4+i)
            #pragma unroll
            for (int i = 0; i < 4; ++i) {
                const float r = sigm(aR[i] + bRr[ti]);
                const float z = sigm(aZ[i] + bZr[ti]);
                const float n = tanhx(aNX[i] + bNXr[ti] + r * (aNH[i] + bNHr[ti]));
                hr[ti][i] = (1.0f - z) * n + z * hr[ti][i];
            }
        }
        __syncthreads();   // B3: all waves done reading XH h-cols
        #pragma unroll
        for (int ti = 0; ti < 2; ++ti) {
            #pragma unroll
            for (int i = 0; i < 4; ++i)
                XH[(quad * 4 + i) * XSTR + INS_ + 32 * wave + 16 * ti + arow] = f2bf(hr[ti][i]);
        }
    }

    // ======== epilogue: out position 95 from h_191 ========
    __syncthreads();
    if (wave < 4) {
        float4_t acc = {0.f, 0.f, 0.f, 0.f};
        #pragma unroll
        for (int kc = 0; kc < 8; ++kc) {
            short8_t a = *(const short8_t*)&XH[arow * XSTR + INS_ + kc * 32 + kq];
            short8_t b = *(const short8_t*)&WD[(wave * 16 + arow) * WDSTR + kc * 32 + kq];
            acc = MFMA16(a, b, acc);
        }
        const int cg = wave * 16 + arow;
        #pragma unroll
        for (int i = 0; i < 4; ++i) {
            const int row = quad * 4 + i;
            out[((size_t)(bb + row) * LOUT_ + 95) * NUM_ + cg] = acc[i] + bdr;
        }
    }
}

// ============ fallback (v1 logic, known-passing fp32) if ws too small ============
__global__ __launch_bounds__(512) void gru_fallback(
    const float* __restrict__ input_num, const int* __restrict__ input_cat,
    const float* __restrict__ emb_table,
    const float* __restrict__ W_ih, const float* __restrict__ W_hh,
    const float* __restrict__ b_ih, const float* __restrict__ b_hh,
    const float* __restrict__ W_dec, const float* __restrict__ b_dec,
    float* __restrict__ out)
{
    __shared__ __align__(16) float xh[4][352];
    __shared__ float wdec[NUM_ * 257];
    const int t = threadIdx.x, bbase = blockIdx.x * 4;
    const int u = t & 255, rb = (t >> 8) * 2;
    for (int i = t; i < NUM_ * HID_; i += 512) wdec[(i >> 8) * 257 + (i & 255)] = W_dec[i];
    for (int i = t; i < 4 * HID_; i += 512) xh[i >> 8][INS_ + (i & 255)] = 0.0f;
    const float bR = b_ih[u] + b_hh[u], bZ = b_ih[256 + u] + b_hh[256 + u];
    const float bNX = b_ih[512 + u], bNH = b_hh[512 + u], bD = b_dec[t & 63];
    __syncthreads();
    auto step = [&]() {
        float aR0 = bR, aR1 = bR, aZ0 = bZ, aZ1 = bZ, aNX0 = bNX, aNX1 = bNX, aNH0 = bNH, aNH1 = bNH;
        const float* x0 = xh[rb]; const float* x1 = xh[rb + 1];
        for (int kb = 0; kb < 88; ++kb) {
            float4 w0, w1, w2; int k4 = kb * 4;
            if (k4 < INS_) {
                w0 = *(const float4*)&W_ih[(size_t)u * INS_ + k4];
                w1 = *(const float4*)&W_ih[(size_t)(256 + u) * INS_ + k4];
                w2 = *(const float4*)&W_ih[(size_t)(512 + u) * INS_ + k4];
            } else {
                int kh = k4 - INS_;
                w0 = *(const float4*)&W_hh[(size_t)u * HID_ + kh];
                w1 = *(const float4*)&W_hh[(size_t)(256 + u) * HID_ + kh];
                w2 = *(const float4*)&W_hh[(size_t)(512 + u) * HID_ + kh];
            }
            float4 a = *(const float4*)&x0[k4], c = *(const float4*)&x1[k4];
            aR0 += w0.x*a.x+w0.y*a.y+w0.z*a.z+w0.w*a.w; aR1 += w0.x*c.x+w0.y*c.y+w0.z*c.z+w0.w*c.w;
            aZ0 += w1.x*a.x+w1.y*a.y+w1.z*a.z+w1.w*a.w; aZ1 += w1.x*c.x+w1.y*c.y+w1.z*c.z+w1.w*c.w;
            if (k4 < INS_) { aNX0 += w2.x*a.x+w2.y*a.y+w2.z*a.z+w2.w*a.w; aNX1 += w2.x*c.x+w2.y*c.y+w2.z*c.z+w2.w*c.w; }
            else           { aNH0 += w2.x*a.x+w2.y*a.y+w2.z*a.z+w2.w*a.w; aNH1 += w2.x*c.x+w2.y*c.y+w2.z*c.z+w2.w*c.w; }
        }
        float h0 = x0[INS_ + u], h1 = x1[INS_ + u];
        __syncthreads();
        { float r = sigm(aR0), z = sigm(aZ0), n = tanhx(aNX0 + r * aNH0);
          xh[rb][INS_ + u] = (1 - z) * n + z * h0; }
        { float r = sigm(aR1), z = sigm(aZ1), n = tanhx(aNX1 + r * aNH1);
          xh[rb + 1][INS_ + u] = (1 - z) * n + z * h1; }
        __syncthreads();
    };
    auto project = [&](int pos) {
        if (t < 256) {
            int r = t >> 6, m = t & 63;
            const float* wr = &wdec[m * 257]; const float* hr2 = &xh[r][INS_];
            float acc = bD;
            for (int k = 0; k < HID_; ++k) acc = fmaf(wr[k], hr2[k], acc);
            out[((size_t)(bbase + r) * LOUT_ + pos) * NUM_ + m] = acc;
            xh[r][m] = acc;
        }
    };
    for (int s = 0; s < LIN_; ++s) {
        if (t < 256) { int r = t >> 6, k = t & 63;
            xh[r][k] = input_num[((size_t)(bbase + r) * TSEQ + s) * NUM_ + k]; }
        if (t < 128) { int r = t >> 5, e = t & 31;
            xh[r][NUM_ + e] = emb_table[input_cat[(bbase + r) * TSEQ + s] * EMB_ + e]; }
        __syncthreads();
        step();
    }
    project(0);
    for (int s = 0; s < LOUT_ - 1; ++s) {
        if (t < 128) { int r = t >> 5, e = t & 31;
            xh[r][NUM_ + e] = emb_table[input_cat[(bbase + r) * TSEQ + LIN_ + s] * EMB_ + e]; }
        __syncthreads();
        step();
        project(s + 1);
    }
}

extern "C" void kernel_launch(void* const* d_in, const int* in_sizes, int n_in,
                              void* d_out, int out_size, void* d_ws, size_t ws_size,
                              hipStream_t stream) {
    const float* input_num = (const float*)d_in[0];
    const int*   input_cat = (const int*)d_in[1];
    const float* emb_table = (const float*)d_in[2];
    const float* W_ih      = (const float*)d_in[3];
    const float* W_hh      = (const float*)d_in[4];
    const float* b_ih      = (const float*)d_in[5];
    const float* b_hh      = (const float*)d_in[6];
    const float* W_dec     = (const float*)d_in[7];
    const float* b_dec     = (const float*)d_in[8];
    float* out = (float*)d_out;

    if (ws_size >= WS_NEED) {
        unsigned char* ws = (unsigned char*)d_ws;
        const int PREP_N = 768 * 160 + 64 * 256;
        prep_v5<<<(PREP_N + 255) / 256, 256, 0, stream>>>(W_hh, W_dec, ws);
        gru_v5<<<NBLK, NT, 0, stream>>>(input_num, input_cat, emb_table,
                                        W_ih, W_hh, b_ih, b_hh, b_dec, ws, out);
    } else {
        gru_fallback<<<BATCH / 4, 512, 0, stream>>>(input_num, input_cat, emb_table,
                                                    W_ih, W_hh, b_ih, b_hh, W_dec, b_dec, out);
    }
}